// Round 17
// baseline (325.861 us; speedup 1.0000x reference)
//
#include <hip/hip_runtime.h>

typedef float f32x4 __attribute__((ext_vector_type(4)));
typedef _Float16 f16x2 __attribute__((ext_vector_type(2)));
typedef _Float16 f16x4 __attribute__((ext_vector_type(4)));
typedef _Float16 f16x8 __attribute__((ext_vector_type(8)));

// ================= CSR build =================
__global__ __launch_bounds__(256) void hist_kernel(const int* __restrict__ dst,
                                                   int* __restrict__ deg, int E) {
  int e = blockIdx.x * 256 + threadIdx.x;
  if (e < E) atomicAdd(&deg[dst[e]], 1);
}

__global__ __launch_bounds__(1024) void scan_kernel(const int* __restrict__ deg,
                                                    int* __restrict__ rowstart,
                                                    int* __restrict__ cursor, int N) {
  __shared__ int sums[1024];
  const int t = threadIdx.x;
  const int CH = (N + 1023) >> 10;
  int local[32];
  int base = t * CH;
  int s = 0;
  for (int i = 0; i < CH; i++) {
    int idx = base + i;
    int v = (idx < N) ? deg[idx] : 0;
    local[i] = s;
    s += v;
  }
  sums[t] = s;
  __syncthreads();
  for (int off = 1; off < 1024; off <<= 1) {
    int add = (t >= off) ? sums[t - off] : 0;
    __syncthreads();
    sums[t] += add;
    __syncthreads();
  }
  int prefix = sums[t] - s;
  for (int i = 0; i < CH; i++) {
    int idx = base + i;
    if (idx < N) {
      int v = prefix + local[i];
      rowstart[idx] = v;
      cursor[idx] = v;
    }
  }
  if (t == 1023) rowstart[N] = sums[1023];
}

__global__ __launch_bounds__(256) void fill_kernel(const int* __restrict__ src,
                                                   const int* __restrict__ dst,
                                                   int* __restrict__ cursor,
                                                   int* __restrict__ nbr, int E) {
  int e = blockIdx.x * 256 + threadIdx.x;
  if (e >= E) return;
  int pos = atomicAdd(&cursor[dst[e]], 1);
  nbr[pos] = src[e];
}

// ================= x0 fp32 -> fp16 =================
__global__ __launch_bounds__(256) void xprep_kernel(const float4* __restrict__ in,
                                                    f16x4* __restrict__ out, int n4) {
  int i = blockIdx.x * 256 + threadIdx.x;
  if (i >= n4) return;
  float4 v = in[i];
  f16x4 h;
  h[0] = (_Float16)v.x; h[1] = (_Float16)v.y;
  h[2] = (_Float16)v.z; h[3] = (_Float16)v.w;
  out[i] = h;
}

// ====== gather over fp16 rows; BN fold (from raw sums) + ReLU fused; fp16 output ======
template <int C, bool BNIN>
__global__ __launch_bounds__(256) void gather_agg_kernel(
    const _Float16* __restrict__ x, const int* __restrict__ rowstart,
    const int* __restrict__ nbr, const float* __restrict__ stats,
    const float* __restrict__ gamma, const float* __restrict__ beta,
    _Float16* __restrict__ agg, int N, float invN) {
  constexpr int Din = 64 * C;
  const int wave = threadIdx.x >> 6;
  const int lane = threadIdx.x & 63;
  const int node = blockIdx.x * 4 + wave;
  if (node >= N) return;

  float sc[C], sh[C];
  if constexpr (BNIN) {
#pragma unroll
    for (int j = 0; j < C; j++) {
      int c = lane * C + j;
      float mean = stats[c] * invN;
      float var = stats[Din + c] * invN - mean * mean;
      sc[j] = rsqrtf(var + 1e-5f) * gamma[c];
      sh[j] = beta[c] - mean * sc[j];
    }
  }

#define LOADROW(dstv, rowidx)                                              \
  {                                                                        \
    const _Float16* _p = x + (size_t)(rowidx)*Din + lane * C;              \
    if constexpr (C == 2) {                                                \
      f16x2 _t = *(const f16x2*)_p;                                        \
      dstv[0] = (float)_t[0]; dstv[1] = (float)_t[1];                      \
    } else {                                                               \
      f16x4 _t = *(const f16x4*)_p;                                        \
      dstv[0] = (float)_t[0]; dstv[1] = (float)_t[1];                      \
      dstv[2] = (float)_t[2]; dstv[3] = (float)_t[3];                      \
    }                                                                      \
  }

  float acc[C];
  {
    float v[C];
    LOADROW(v, node)
#pragma unroll
    for (int j = 0; j < C; j++)
      acc[j] = BNIN ? fmaxf(v[j] * sc[j] + sh[j], 0.f) : v[j];
  }
  const int rs = rowstart[node], re = rowstart[node + 1];
  int e = rs;
  for (; e + 1 < re; e += 2) {
    int s0 = nbr[e], s1 = nbr[e + 1];
    float v0[C], v1[C];
    LOADROW(v0, s0)
    LOADROW(v1, s1)
#pragma unroll
    for (int j = 0; j < C; j++) {
      acc[j] += BNIN ? fmaxf(v0[j] * sc[j] + sh[j], 0.f) : v0[j];
      acc[j] += BNIN ? fmaxf(v1[j] * sc[j] + sh[j], 0.f) : v1[j];
    }
  }
  if (e < re) {
    int s0 = nbr[e];
    float v0[C];
    LOADROW(v0, s0)
#pragma unroll
    for (int j = 0; j < C; j++)
      acc[j] += BNIN ? fmaxf(v0[j] * sc[j] + sh[j], 0.f) : v0[j];
  }
#undef LOADROW

  _Float16* o = agg + (size_t)node * Din + lane * C;
  if constexpr (C == 2) {
    f16x2 r; r[0] = (_Float16)acc[0]; r[1] = (_Float16)acc[1];
    *(f16x2*)o = r;
  } else {
    f16x4 r;
    r[0] = (_Float16)acc[0]; r[1] = (_Float16)acc[1];
    r[2] = (_Float16)acc[2]; r[3] = (_Float16)acc[3];
    *(f16x4*)o = r;
  }
}

// ================= batched weight prep: W[K][N] fp32 -> WT [N][K] fp16 =================
struct WSeg {
  const float* W;
  _Float16* TH;
  int K, N, total;
};
struct WAll { WSeg s[6]; };

__global__ __launch_bounds__(256) void wprep_all_kernel(WAll a) {
  WSeg sg = a.s[blockIdx.y];
  int idx = blockIdx.x * 256 + threadIdx.x;
  if (idx >= sg.total) return;
  int k = idx / sg.N, n = idx - k * sg.N;
  sg.TH[(size_t)n * sg.K + k] = (_Float16)sg.W[idx];
}

// ===== fused MLP: h2 = (relu(A @ W1 + b1)) @ W2 + b2, all fp16 in/out, fp32 accum =====
// Block: 32 rows x DOUT cols, 4 waves (wave = DOUT/4 cols). A staged once; h1 lives in LDS.
// Phase 1 uses swapped MFMA operands (out: row=lane&15, col=(lane>>4)*4+reg) so h1 packs
// into LDS fragment layout with ds_write_b64. Phase 2 is the standard layout + stats.
template <int DIN, int DOUT>
__global__ __launch_bounds__(256) void mlp_kernel(
    const _Float16* __restrict__ A, const _Float16* __restrict__ B1T,
    const float* __restrict__ bias1, const _Float16* __restrict__ B2T,
    const float* __restrict__ bias2, _Float16* __restrict__ H2,
    int M, float* __restrict__ stats) {
  constexpr int CW = DOUT / 4;   // cols per wave
  constexpr int NCF = CW / 16;   // col frags per wave
  constexpr int KS1 = DIN / 32;
  constexpr int KS2 = DOUT / 32;
  __shared__ _Float16 Atile[32 * DIN];
  __shared__ _Float16 H1[32 * DOUT];

  const int tid = threadIdx.x;
  const int lane = tid & 63;
  const int w = tid >> 6;
  const int rowBase = blockIdx.x * 32;
  const int colBase = w * CW;
  const int c0 = colBase + (lane & 15);
  const int kf = (lane >> 4) * 8;

  // ---- stage A tile (32 x DIN) once, fragment-linear ----
  {
    const int srow = tid >> 3;
    const int c8 = tid & 7;
    const size_t aoff = (size_t)(rowBase + srow) * DIN;
    const bool ok = (rowBase + srow) < M;
#pragma unroll
    for (int i = 0; i < DIN / 64; i++) {
      int k = c8 * 8 + i * 64;
      f16x8 h8 = {};
      if (ok) h8 = *(const f16x8*)(A + aoff + k);
      int frag = (k >> 5) * 2 + (srow >> 4);
      int slot = (srow & 15) | (((k >> 3) & 3) << 4);
      *(f16x8*)(Atile + frag * 512 + slot * 8) = h8;
    }
  }
  __syncthreads();

  // ---- phase 1: h1 = relu(A @ W1 + b1), swapped operands, output to LDS ----
  {
    f32x4 acc[2][NCF] = {};
#pragma unroll
    for (int ks = 0; ks < KS1; ks++) {
      f16x8 b1[NCF];
#pragma unroll
      for (int cf = 0; cf < NCF; cf++)
        b1[cf] = *(const f16x8*)(B1T + (size_t)(c0 + cf * 16) * DIN + ks * 32 + kf);
#pragma unroll
      for (int fi = 0; fi < 2; fi++) {
        f16x8 a = *(const f16x8*)(Atile + (ks * 2 + fi) * 512 + lane * 8);
#pragma unroll
        for (int cf = 0; cf < NCF; cf++)
          acc[fi][cf] = __builtin_amdgcn_mfma_f32_16x16x32_f16(b1[cf], a, acc[fi][cf], 0, 0, 0);
      }
    }
#pragma unroll
    for (int cf = 0; cf < NCF; cf++) {
      const int c = colBase + cf * 16 + (lane >> 4) * 4;
      float4 b4 = *(const float4*)(bias1 + c);
#pragma unroll
      for (int fi = 0; fi < 2; fi++) {
        f16x4 hv;
#pragma unroll
        for (int j = 0; j < 4; j++)
          hv[j] = (_Float16)fmaxf(acc[fi][cf][j] + ((const float*)&b4)[j], 0.f);
        int frag = (c >> 5) * 2 + fi;
        int slot = (lane & 15) | (((c >> 3) & 3) << 4);
        *(f16x4*)(H1 + frag * 512 + slot * 8 + (c & 7)) = hv;
      }
    }
  }
  __syncthreads();

  // ---- phase 2: h2 = h1 @ W2 + b2 (standard layout) + fp32 column stats ----
  {
    f32x4 acc[2][NCF] = {};
#pragma unroll
    for (int ks = 0; ks < KS2; ks++) {
      f16x8 b2[NCF];
#pragma unroll
      for (int cf = 0; cf < NCF; cf++)
        b2[cf] = *(const f16x8*)(B2T + (size_t)(c0 + cf * 16) * DOUT + ks * 32 + kf);
#pragma unroll
      for (int fi = 0; fi < 2; fi++) {
        f16x8 a = *(const f16x8*)(H1 + (ks * 2 + fi) * 512 + lane * 8);
#pragma unroll
        for (int cf = 0; cf < NCF; cf++)
          acc[fi][cf] = __builtin_amdgcn_mfma_f32_16x16x32_f16(a, b2[cf], acc[fi][cf], 0, 0, 0);
      }
    }
    float bs[NCF], s1[NCF], s2[NCF];
#pragma unroll
    for (int cf = 0; cf < NCF; cf++) {
      bs[cf] = bias2[c0 + cf * 16];
      s1[cf] = 0.f; s2[cf] = 0.f;
    }
    const int rbase = rowBase + (lane >> 4) * 4;
#pragma unroll
    for (int fi = 0; fi < 2; fi++) {
#pragma unroll
      for (int j = 0; j < 4; j++) {
        int row = rbase + fi * 16 + j;
        if (row < M) {
#pragma unroll
          for (int cf = 0; cf < NCF; cf++) {
            float v = acc[fi][cf][j] + bs[cf];
            H2[(size_t)row * DOUT + c0 + cf * 16] = (_Float16)v;
            s1[cf] += v; s2[cf] += v * v;
          }
        }
      }
    }
#pragma unroll
    for (int cf = 0; cf < NCF; cf++) {
#pragma unroll
      for (int off = 16; off < 64; off <<= 1) {
        s1[cf] += __shfl_xor(s1[cf], off);
        s2[cf] += __shfl_xor(s2[cf], off);
      }
    }
    if (lane < 16) {
#pragma unroll
      for (int cf = 0; cf < NCF; cf++) {
        atomicAdd(&stats[c0 + cf * 16], s1[cf]);
        atomicAdd(&stats[DOUT + c0 + cf * 16], s2[cf]);
      }
    }
  }
}

// ====== fused BN(fold from raw sums)+ReLU+segment-mean pool (layer 3, D=512) ======
__global__ __launch_bounds__(256) void bn_pool_kernel(
    const _Float16* __restrict__ h, const float* __restrict__ stats,
    const float* __restrict__ gamma, const float* __restrict__ beta,
    const int* __restrict__ batch, float* __restrict__ pooled, int N, float invN) {
  const int g = blockIdx.x >> 3;
  const int s = blockIdx.x & 7;
  __shared__ int s_lo, s_hi;
  if (threadIdx.x == 0) {
    int lo = 0, hi = N;
    while (lo < hi) { int m = (lo + hi) >> 1; if (batch[m] < g) lo = m + 1; else hi = m; }
    s_lo = lo;
    lo = 0; hi = N;
    while (lo < hi) { int m = (lo + hi) >> 1; if (batch[m] < g + 1) lo = m + 1; else hi = m; }
    s_hi = lo;
  }
  __syncthreads();
  const int lo = s_lo, hi = s_hi, len = hi - lo;
  if (len == 0) return;
  const int per = (len + 7) >> 3;
  const int rs = lo + s * per;
  const int re = min(rs + per, hi);
  if (rs >= re) return;
  const int t = threadIdx.x;
  float scv[2], shv[2];
#pragma unroll
  for (int j = 0; j < 2; j++) {
    int c = 2 * t + j;
    float mean = stats[c] * invN;
    float var = stats[512 + c] * invN - mean * mean;
    scv[j] = rsqrtf(var + 1e-5f) * gamma[c];
    shv[j] = beta[c] - mean * scv[j];
  }
  float ax = 0.f, ay = 0.f;
  for (int r = rs; r < re; r++) {
    f16x2 v = *(const f16x2*)(h + (size_t)r * 512 + 2 * t);
    ax += fmaxf((float)v[0] * scv[0] + shv[0], 0.f);
    ay += fmaxf((float)v[1] * scv[1] + shv[1], 0.f);
  }
  float inv = 1.f / (float)len;
  atomicAdd(&pooled[g * 512 + 2 * t], ax * inv);
  atomicAdd(&pooled[g * 512 + 2 * t + 1], ay * inv);
}

// ================= final projection =================
__global__ __launch_bounds__(64) void out_kernel(const float* __restrict__ pooled,
                                                 const float* __restrict__ wo,
                                                 const float* __restrict__ bo,
                                                 float* __restrict__ out) {
  int g = blockIdx.x, o = threadIdx.x;
  float acc = bo[o];
  for (int c = 0; c < 512; c++) acc += pooled[g * 512 + c] * wo[c * 64 + o];
  out[g * 64 + o] = fmaxf(acc, 0.f);
}

extern "C" void kernel_launch(void* const* d_in, const int* in_sizes, int n_in,
                              void* d_out, int out_size, void* d_ws, size_t ws_size,
                              hipStream_t stream) {
  const float* x0 = (const float*)d_in[0];
  const int* ei = (const int*)d_in[1];
  const int* batch = (const int*)d_in[2];
  const int N = in_sizes[0] / 128;
  const int E = in_sizes[1] / 2;
  const int* src = ei;
  const int* dst = ei + E;
  const float* W[3][6];
  for (int li = 0; li < 3; li++)
    for (int k = 0; k < 6; k++) W[li][k] = (const float*)d_in[3 + li * 6 + k];
  const float* wo = (const float*)d_in[21];
  const float* bo = (const float*)d_in[22];
  float* out = (float*)d_out;

  // workspace layout
  float* stats3 = (float*)d_ws;              // 3*1024
  float* pooled = stats3 + 3 * 1024;         // 64*512
  int* deg = (int*)(pooled + 64 * 512);      // N
  int* rowstart = deg + N;                   // N+1
  int* cursor = rowstart + N + 1;            // N
  int* nbr = cursor + N;                     // E
  uintptr_t wp = (uintptr_t)(nbr + E);
  wp = (wp + 15) & ~(uintptr_t)15;
  _Float16* aggh = (_Float16*)wp;            // N*256 f16
  _Float16* h2h = aggh + (size_t)N * 256;    // N*512 f16
  _Float16* x0h = h2h + (size_t)N * 512;     // N*128 f16
  _Float16* wbuf = x0h + (size_t)N * 128;

  const int dins[3] = {128, 128, 256};
  const int douts[3] = {128, 256, 512};

  _Float16* WT[3][2];
  {
    _Float16* p = wbuf;
    for (int li = 0; li < 3; li++) {
      WT[li][0] = p; p += (size_t)dins[li] * douts[li];
      WT[li][1] = p; p += (size_t)douts[li] * douts[li];
    }
  }
  // batched weight prep (1 launch)
  {
    WAll wa;
    int maxTotal = 0;
    for (int li = 0; li < 3; li++) {
      int e1 = dins[li] * douts[li];
      int e2 = douts[li] * douts[li];
      wa.s[li * 2 + 0] = WSeg{W[li][0], WT[li][0], dins[li], douts[li], e1};
      wa.s[li * 2 + 1] = WSeg{W[li][2], WT[li][1], douts[li], douts[li], e2};
      maxTotal = max(maxTotal, max(e1, e2));
    }
    dim3 g((maxTotal + 255) / 256, 6);
    wprep_all_kernel<<<g, 256, 0, stream>>>(wa);
  }

  // x0 -> fp16
  {
    int n4 = N * 32;
    xprep_kernel<<<(n4 + 255) / 256, 256, 0, stream>>>((const float4*)x0, (f16x4*)x0h, n4);
  }

  // CSR build
  hipMemsetAsync(deg, 0, (size_t)N * sizeof(int), stream);
  hist_kernel<<<(E + 255) / 256, 256, 0, stream>>>(dst, deg, E);
  scan_kernel<<<1, 1024, 0, stream>>>(deg, rowstart, cursor, N);
  fill_kernel<<<(E + 255) / 256, 256, 0, stream>>>(src, dst, cursor, nbr, E);

  // zero stats + pooled in one shot
  hipMemsetAsync(stats3, 0, (3 * 1024 + 64 * 512) * sizeof(float), stream);

  const int mb32 = (N + 31) / 32;
  const int gblocks = (N + 3) / 4;
  const float invN = 1.0f / N;

  // layer 1: 128 -> 128
  gather_agg_kernel<2, false><<<gblocks, 256, 0, stream>>>(
      x0h, rowstart, nbr, nullptr, nullptr, nullptr, aggh, N, invN);
  mlp_kernel<128, 128><<<mb32, 256, 0, stream>>>(
      aggh, WT[0][0], W[0][1], WT[0][1], W[0][3], h2h, N, stats3 + 0 * 1024);

  // layer 2: 128 -> 256
  gather_agg_kernel<2, true><<<gblocks, 256, 0, stream>>>(
      h2h, rowstart, nbr, stats3 + 0 * 1024, W[0][4], W[0][5], aggh, N, invN);
  mlp_kernel<128, 256><<<mb32, 256, 0, stream>>>(
      aggh, WT[1][0], W[1][1], WT[1][1], W[1][3], h2h, N, stats3 + 1 * 1024);

  // layer 3: 256 -> 512
  gather_agg_kernel<4, true><<<gblocks, 256, 0, stream>>>(
      h2h, rowstart, nbr, stats3 + 1 * 1024, W[1][4], W[1][5], aggh, N, invN);
  mlp_kernel<256, 512><<<mb32, 256, 0, stream>>>(
      aggh, WT[2][0], W[2][1], WT[2][1], W[2][3], h2h, N, stats3 + 2 * 1024);

  // pool + output
  bn_pool_kernel<<<64 * 8, 256, 0, stream>>>(
      h2h, stats3 + 2 * 1024, W[2][4], W[2][5], batch, pooled, N, invN);
  out_kernel<<<64, 64, 0, stream>>>(pooled, wo, bo, out);
}

// Round 18
// 289.331 us; speedup vs baseline: 1.1263x; 1.1263x over previous
//
#include <hip/hip_runtime.h>

typedef float f32x4 __attribute__((ext_vector_type(4)));
typedef _Float16 f16x2 __attribute__((ext_vector_type(2)));
typedef _Float16 f16x4 __attribute__((ext_vector_type(4)));
typedef _Float16 f16x8 __attribute__((ext_vector_type(8)));

// ================= CSR build =================
__global__ __launch_bounds__(256) void hist_kernel(const int* __restrict__ dst,
                                                   int* __restrict__ deg, int E) {
  int e = blockIdx.x * 256 + threadIdx.x;
  if (e < E) atomicAdd(&deg[dst[e]], 1);
}

__global__ __launch_bounds__(1024) void scan_kernel(const int* __restrict__ deg,
                                                    int* __restrict__ rowstart,
                                                    int* __restrict__ cursor, int N) {
  __shared__ int sums[1024];
  const int t = threadIdx.x;
  const int CH = (N + 1023) >> 10;
  int local[32];
  int base = t * CH;
  int s = 0;
  for (int i = 0; i < CH; i++) {
    int idx = base + i;
    int v = (idx < N) ? deg[idx] : 0;
    local[i] = s;
    s += v;
  }
  sums[t] = s;
  __syncthreads();
  for (int off = 1; off < 1024; off <<= 1) {
    int add = (t >= off) ? sums[t - off] : 0;
    __syncthreads();
    sums[t] += add;
    __syncthreads();
  }
  int prefix = sums[t] - s;
  for (int i = 0; i < CH; i++) {
    int idx = base + i;
    if (idx < N) {
      int v = prefix + local[i];
      rowstart[idx] = v;
      cursor[idx] = v;
    }
  }
  if (t == 1023) rowstart[N] = sums[1023];
}

__global__ __launch_bounds__(256) void fill_kernel(const int* __restrict__ src,
                                                   const int* __restrict__ dst,
                                                   int* __restrict__ cursor,
                                                   int* __restrict__ nbr, int E) {
  int e = blockIdx.x * 256 + threadIdx.x;
  if (e >= E) return;
  int pos = atomicAdd(&cursor[dst[e]], 1);
  nbr[pos] = src[e];
}

// ================= x0 fp32 -> fp16 =================
__global__ __launch_bounds__(256) void xprep_kernel(const float4* __restrict__ in,
                                                    f16x4* __restrict__ out, int n4) {
  int i = blockIdx.x * 256 + threadIdx.x;
  if (i >= n4) return;
  float4 v = in[i];
  f16x4 h;
  h[0] = (_Float16)v.x; h[1] = (_Float16)v.y;
  h[2] = (_Float16)v.z; h[3] = (_Float16)v.w;
  out[i] = h;
}

// ====== gather over fp16 rows; BN fold (from raw sums) + ReLU fused; fp16 output ======
template <int C, bool BNIN>
__global__ __launch_bounds__(256) void gather_agg_kernel(
    const _Float16* __restrict__ x, const int* __restrict__ rowstart,
    const int* __restrict__ nbr, const float* __restrict__ stats,
    const float* __restrict__ gamma, const float* __restrict__ beta,
    _Float16* __restrict__ agg, int N, float invN) {
  constexpr int Din = 64 * C;
  const int wave = threadIdx.x >> 6;
  const int lane = threadIdx.x & 63;
  const int node = blockIdx.x * 4 + wave;
  if (node >= N) return;

  float sc[C], sh[C];
  if constexpr (BNIN) {
#pragma unroll
    for (int j = 0; j < C; j++) {
      int c = lane * C + j;
      float mean = stats[c] * invN;
      float var = stats[Din + c] * invN - mean * mean;
      sc[j] = rsqrtf(var + 1e-5f) * gamma[c];
      sh[j] = beta[c] - mean * sc[j];
    }
  }

#define LOADROW(dstv, rowidx)                                              \
  {                                                                        \
    const _Float16* _p = x + (size_t)(rowidx)*Din + lane * C;              \
    if constexpr (C == 2) {                                                \
      f16x2 _t = *(const f16x2*)_p;                                        \
      dstv[0] = (float)_t[0]; dstv[1] = (float)_t[1];                      \
    } else {                                                               \
      f16x4 _t = *(const f16x4*)_p;                                        \
      dstv[0] = (float)_t[0]; dstv[1] = (float)_t[1];                      \
      dstv[2] = (float)_t[2]; dstv[3] = (float)_t[3];                      \
    }                                                                      \
  }
#define ACCUM(vv)                                                          \
  _Pragma("unroll") for (int j = 0; j < C; j++)                            \
      acc[j] += BNIN ? fmaxf(vv[j] * sc[j] + sh[j], 0.f) : vv[j];

  float acc[C];
  {
    float v[C];
    LOADROW(v, node)
#pragma unroll
    for (int j = 0; j < C; j++)
      acc[j] = BNIN ? fmaxf(v[j] * sc[j] + sh[j], 0.f) : v[j];
  }
  const int rs = rowstart[node], re = rowstart[node + 1];
  int e = rs;
  for (; e + 3 < re; e += 4) {
    int s0 = nbr[e], s1 = nbr[e + 1], s2 = nbr[e + 2], s3 = nbr[e + 3];
    float v0[C], v1[C], v2[C], v3[C];
    LOADROW(v0, s0)
    LOADROW(v1, s1)
    LOADROW(v2, s2)
    LOADROW(v3, s3)
    ACCUM(v0) ACCUM(v1) ACCUM(v2) ACCUM(v3)
  }
  for (; e + 1 < re; e += 2) {
    int s0 = nbr[e], s1 = nbr[e + 1];
    float v0[C], v1[C];
    LOADROW(v0, s0)
    LOADROW(v1, s1)
    ACCUM(v0) ACCUM(v1)
  }
  if (e < re) {
    int s0 = nbr[e];
    float v0[C];
    LOADROW(v0, s0)
    ACCUM(v0)
  }
#undef ACCUM
#undef LOADROW

  _Float16* o = agg + (size_t)node * Din + lane * C;
  if constexpr (C == 2) {
    f16x2 r; r[0] = (_Float16)acc[0]; r[1] = (_Float16)acc[1];
    *(f16x2*)o = r;
  } else {
    f16x4 r;
    r[0] = (_Float16)acc[0]; r[1] = (_Float16)acc[1];
    r[2] = (_Float16)acc[2]; r[3] = (_Float16)acc[3];
    *(f16x4*)o = r;
  }
}

// ================= batched weight prep: W[K][N] fp32 -> WT [N][K] fp16 =================
struct WSeg {
  const float* W;
  _Float16* TH;
  int K, N, total;
};
struct WAll { WSeg s[6]; };

__global__ __launch_bounds__(256) void wprep_all_kernel(WAll a) {
  WSeg sg = a.s[blockIdx.y];
  int idx = blockIdx.x * 256 + threadIdx.x;
  if (idx >= sg.total) return;
  int k = idx / sg.N, n = idx - k * sg.N;
  sg.TH[(size_t)n * sg.K + k] = (_Float16)sg.W[idx];
}

// ===== MFMA GEMM: C = A[MxK] @ B[KxN] + bias, all-FP16 inputs (fp32 accumulate) =====
// r10/r16 structure: RT rows x 128 cols per block, 4 waves, BK=64; XCD swizzle.
template <int RT>
__global__ __launch_bounds__(256, 8) void gemm_mfma_kernel(
    const _Float16* __restrict__ A, const _Float16* __restrict__ BT,
    const float* __restrict__ bias, _Float16* __restrict__ Ch,
    int M, int K, int N, int mblocks, int cbShift,
    int doRelu, float* __restrict__ stats) {
  constexpr int NF = RT / 16;
  constexpr int NP = RT / 32;
  __shared__ _Float16 Ah[2 * NF * 512];
  const int bid = blockIdx.x;
  const int xcd = bid & 7;
  const int q = bid >> 3;
  const int r = ((q >> cbShift) << 3) + xcd;
  const int cb = q & ((1 << cbShift) - 1);
  if (r >= mblocks) return;

  const int tid = threadIdx.x;
  const int lane = tid & 63;
  const int w = tid >> 6;
  const int rowBase = r * RT;
  const int colBase = cb * 128 + w * 32;

  f32x4 acc[NF][2] = {};

  const int c0 = colBase + (lane & 15);
  const int kfrag = (lane >> 4) * 8;

  int srow, slane, sfrag0, kk0;
  if constexpr (RT == 64) {
    srow = tid >> 2;
    const int schunk = tid & 3;
    slane = (srow & 15) | (schunk << 4);
    sfrag0 = srow >> 4;
    kk0 = schunk * 8;
  } else {
    srow = tid >> 3;
    const int c8 = tid & 7;
    const int lc = c8 & 3, ks = c8 >> 2;
    slane = (srow & 15) | (lc << 4);
    sfrag0 = ks * NF + (srow >> 4);
    kk0 = lc * 8 + ks * 32;
  }
  const size_t arowOff = (size_t)(rowBase + srow) * K;
  const bool srowOk = (rowBase + srow) < M;

  for (int k0 = 0; k0 < K; k0 += 64) {
#pragma unroll
    for (int i = 0; i < NP; i++) {
      int kk = k0 + kk0 + (RT == 64 ? i * 32 : 0);
      f16x8 h8 = {};
      if (srowOk) h8 = *(const f16x8*)(A + arowOff + kk);
      int frag = (RT == 64 ? i * NF + sfrag0 : sfrag0);
      *(f16x8*)(Ah + frag * 512 + slane * 8) = h8;
    }
    __syncthreads();
#pragma unroll
    for (int ks = 0; ks < 2; ks++) {
      int kidx = k0 + ks * 32 + kfrag;
      f16x8 bh0 = *(const f16x8*)(BT + (size_t)c0 * K + kidx);
      f16x8 bh1 = *(const f16x8*)(BT + (size_t)(c0 + 16) * K + kidx);
#pragma unroll
      for (int fi = 0; fi < NF; fi++) {
        int frag = ks * NF + fi;
        f16x8 ah = *(const f16x8*)(Ah + frag * 512 + lane * 8);
        acc[fi][0] = __builtin_amdgcn_mfma_f32_16x16x32_f16(ah, bh0, acc[fi][0], 0, 0, 0);
        acc[fi][1] = __builtin_amdgcn_mfma_f32_16x16x32_f16(ah, bh1, acc[fi][1], 0, 0, 0);
      }
    }
    __syncthreads();
  }

  // epilogue
  const float bias0 = bias[c0], bias1 = bias[c0 + 16];
  float s1[2] = {0.f, 0.f}, s2[2] = {0.f, 0.f};
  const int rbase = rowBase + (lane >> 4) * 4;
#pragma unroll
  for (int fi = 0; fi < NF; fi++) {
#pragma unroll
    for (int j = 0; j < 4; j++) {
      int row = rbase + fi * 16 + j;
      float v0 = acc[fi][0][j] + bias0;
      float v1 = acc[fi][1][j] + bias1;
      if (doRelu) { v0 = fmaxf(v0, 0.f); v1 = fmaxf(v1, 0.f); }
      if (row < M) {
        Ch[(size_t)row * N + c0] = (_Float16)v0;
        Ch[(size_t)row * N + c0 + 16] = (_Float16)v1;
        s1[0] += v0; s2[0] += v0 * v0;
        s1[1] += v1; s2[1] += v1 * v1;
      }
    }
  }
  if (stats) {
#pragma unroll
    for (int off = 16; off < 64; off <<= 1) {
      s1[0] += __shfl_xor(s1[0], off);
      s2[0] += __shfl_xor(s2[0], off);
      s1[1] += __shfl_xor(s1[1], off);
      s2[1] += __shfl_xor(s2[1], off);
    }
    if (lane < 16) {
      atomicAdd(&stats[c0], s1[0]);
      atomicAdd(&stats[N + c0], s2[0]);
      atomicAdd(&stats[c0 + 16], s1[1]);
      atomicAdd(&stats[N + c0 + 16], s2[1]);
    }
  }
}

// ====== fused BN(fold from raw sums)+ReLU+segment-mean pool (layer 3, D=512) ======
__global__ __launch_bounds__(256) void bn_pool_kernel(
    const _Float16* __restrict__ h, const float* __restrict__ stats,
    const float* __restrict__ gamma, const float* __restrict__ beta,
    const int* __restrict__ batch, float* __restrict__ pooled, int N, float invN) {
  const int g = blockIdx.x >> 3;
  const int s = blockIdx.x & 7;
  __shared__ int s_lo, s_hi;
  if (threadIdx.x == 0) {
    int lo = 0, hi = N;
    while (lo < hi) { int m = (lo + hi) >> 1; if (batch[m] < g) lo = m + 1; else hi = m; }
    s_lo = lo;
    lo = 0; hi = N;
    while (lo < hi) { int m = (lo + hi) >> 1; if (batch[m] < g + 1) lo = m + 1; else hi = m; }
    s_hi = lo;
  }
  __syncthreads();
  const int lo = s_lo, hi = s_hi, len = hi - lo;
  if (len == 0) return;
  const int per = (len + 7) >> 3;
  const int rs = lo + s * per;
  const int re = min(rs + per, hi);
  if (rs >= re) return;
  const int t = threadIdx.x;
  float scv[2], shv[2];
#pragma unroll
  for (int j = 0; j < 2; j++) {
    int c = 2 * t + j;
    float mean = stats[c] * invN;
    float var = stats[512 + c] * invN - mean * mean;
    scv[j] = rsqrtf(var + 1e-5f) * gamma[c];
    shv[j] = beta[c] - mean * scv[j];
  }
  float ax = 0.f, ay = 0.f;
  for (int r = rs; r < re; r++) {
    f16x2 v = *(const f16x2*)(h + (size_t)r * 512 + 2 * t);
    ax += fmaxf((float)v[0] * scv[0] + shv[0], 0.f);
    ay += fmaxf((float)v[1] * scv[1] + shv[1], 0.f);
  }
  float inv = 1.f / (float)len;
  atomicAdd(&pooled[g * 512 + 2 * t], ax * inv);
  atomicAdd(&pooled[g * 512 + 2 * t + 1], ay * inv);
}

// ================= final projection =================
__global__ __launch_bounds__(64) void out_kernel(const float* __restrict__ pooled,
                                                 const float* __restrict__ wo,
                                                 const float* __restrict__ bo,
                                                 float* __restrict__ out) {
  int g = blockIdx.x, o = threadIdx.x;
  float acc = bo[o];
  for (int c = 0; c < 512; c++) acc += pooled[g * 512 + c] * wo[c * 64 + o];
  out[g * 64 + o] = fmaxf(acc, 0.f);
}

extern "C" void kernel_launch(void* const* d_in, const int* in_sizes, int n_in,
                              void* d_out, int out_size, void* d_ws, size_t ws_size,
                              hipStream_t stream) {
  const float* x0 = (const float*)d_in[0];
  const int* ei = (const int*)d_in[1];
  const int* batch = (const int*)d_in[2];
  const int N = in_sizes[0] / 128;
  const int E = in_sizes[1] / 2;
  const int* src = ei;
  const int* dst = ei + E;
  const float* W[3][6];
  for (int li = 0; li < 3; li++)
    for (int k = 0; k < 6; k++) W[li][k] = (const float*)d_in[3 + li * 6 + k];
  const float* wo = (const float*)d_in[21];
  const float* bo = (const float*)d_in[22];
  float* out = (float*)d_out;

  // workspace layout
  float* stats3 = (float*)d_ws;              // 3*1024
  float* pooled = stats3 + 3 * 1024;         // 64*512
  int* deg = (int*)(pooled + 64 * 512);      // N
  int* rowstart = deg + N;                   // N+1
  int* cursor = rowstart + N + 1;            // N
  int* nbr = cursor + N;                     // E
  uintptr_t wp = (uintptr_t)(nbr + E);
  wp = (wp + 15) & ~(uintptr_t)15;
  _Float16* aggh = (_Float16*)wp;            // N*256 f16
  _Float16* h1h = aggh + (size_t)N * 256;    // N*512 f16
  _Float16* h2h = h1h + (size_t)N * 512;     // N*512 f16
  _Float16* x0h = h2h + (size_t)N * 512;     // N*128 f16
  _Float16* wbuf = x0h + (size_t)N * 128;

  const int dins[3] = {128, 128, 256};
  const int douts[3] = {128, 256, 512};

  _Float16* WT[3][2];
  {
    _Float16* p = wbuf;
    for (int li = 0; li < 3; li++) {
      WT[li][0] = p; p += (size_t)dins[li] * douts[li];
      WT[li][1] = p; p += (size_t)douts[li] * douts[li];
    }
  }
  // batched weight prep (1 launch)
  {
    WAll wa;
    int maxTotal = 0;
    for (int li = 0; li < 3; li++) {
      int e1 = dins[li] * douts[li];
      int e2 = douts[li] * douts[li];
      wa.s[li * 2 + 0] = WSeg{W[li][0], WT[li][0], dins[li], douts[li], e1};
      wa.s[li * 2 + 1] = WSeg{W[li][2], WT[li][1], douts[li], douts[li], e2};
      maxTotal = max(maxTotal, max(e1, e2));
    }
    dim3 g((maxTotal + 255) / 256, 6);
    wprep_all_kernel<<<g, 256, 0, stream>>>(wa);
  }

  // x0 -> fp16
  {
    int n4 = N * 32;
    xprep_kernel<<<(n4 + 255) / 256, 256, 0, stream>>>((const float4*)x0, (f16x4*)x0h, n4);
  }

  // CSR build
  hipMemsetAsync(deg, 0, (size_t)N * sizeof(int), stream);
  hist_kernel<<<(E + 255) / 256, 256, 0, stream>>>(dst, deg, E);
  scan_kernel<<<1, 1024, 0, stream>>>(deg, rowstart, cursor, N);
  fill_kernel<<<(E + 255) / 256, 256, 0, stream>>>(src, dst, cursor, nbr, E);

  // zero stats + pooled in one shot
  hipMemsetAsync(stats3, 0, (3 * 1024 + 64 * 512) * sizeof(float), stream);

  const int mb64 = (N + 63) / 64;
  const int mb64_8 = ((mb64 + 7) / 8) * 8;
  const int mb32 = (N + 31) / 32;
  const int mb32_8 = ((mb32 + 7) / 8) * 8;
  const int gblocks = (N + 3) / 4;
  const float invN = 1.0f / N;

  for (int li = 0; li < 3; li++) {
    int Din = dins[li], Dout = douts[li];
    float* stats = stats3 + li * 1024;
    if (li == 0)
      gather_agg_kernel<2, false><<<gblocks, 256, 0, stream>>>(
          x0h, rowstart, nbr, nullptr, nullptr, nullptr, aggh, N, invN);
    else if (li == 1)
      gather_agg_kernel<2, true><<<gblocks, 256, 0, stream>>>(
          h2h, rowstart, nbr, stats3 + 0 * 1024, W[0][4], W[0][5], aggh, N, invN);
    else
      gather_agg_kernel<4, true><<<gblocks, 256, 0, stream>>>(
          h2h, rowstart, nbr, stats3 + 1 * 1024, W[1][4], W[1][5], aggh, N, invN);

    if (Dout == 128) {
      gemm_mfma_kernel<32><<<mb32_8, 256, 0, stream>>>(aggh, WT[li][0], W[li][1], h1h,
                                                       N, Din, Dout, mb32, 0, 1, nullptr);
      gemm_mfma_kernel<32><<<mb32_8, 256, 0, stream>>>(h1h, WT[li][1], W[li][3], h2h,
                                                       N, Dout, Dout, mb32, 0, 0, stats);
    } else {
      int cbShift = (Dout == 256) ? 1 : 2;
      int nblocks = mb64_8 << cbShift;
      gemm_mfma_kernel<64><<<nblocks, 256, 0, stream>>>(aggh, WT[li][0], W[li][1], h1h,
                                                        N, Din, Dout, mb64, cbShift, 1, nullptr);
      gemm_mfma_kernel<64><<<nblocks, 256, 0, stream>>>(h1h, WT[li][1], W[li][3], h2h,
                                                        N, Dout, Dout, mb64, cbShift, 0, stats);
    }
    if (li == 2) {
      bn_pool_kernel<<<64 * 8, 256, 0, stream>>>(
          h2h, stats3 + 2 * 1024, W[2][4], W[2][5], batch, pooled, N, invN);
    }
  }
  out_kernel<<<64, 64, 0, stream>>>(pooled, wo, bo, out);
}